// Round 3
// baseline (1957.686 us; speedup 1.0000x reference)
//
#include <hip/hip_runtime.h>
#include <math.h>

#define N_TOK 16384
#define DIM   1024
#define DFF_  4096
#define NE    8
#define MAXT2 136               // sum ceil(n_e/256) <= 8 + 32768/256 = 136
#define MAXSLOTS2 (MAXT2*256)   // 34816

typedef __attribute__((ext_vector_type(8))) __bf16 bf16x8;
typedef __attribute__((ext_vector_type(4))) float  f32x4;
typedef __attribute__((ext_vector_type(8))) unsigned short u16x8;

__device__ __forceinline__ unsigned short f2bf(float f) {
    union { float f; unsigned int u; } v; v.f = f;
    unsigned int u = v.u;
    unsigned int r = (u + 0x7fffu + ((u >> 16) & 1u)) >> 16;  // RNE
    return (unsigned short)r;
}

__device__ __forceinline__ float gelu_t(float x) {
    // tanh-approx gelu; |err vs erf-gelu| <= ~3e-3 (absmax headroom ~9x)
    float u = 0.7978845608028654f * (x + 0.044715f * x * x * x);
    float ex = __expf(2.0f * u);
    float th = 1.0f - 2.0f / (ex + 1.0f);
    return 0.5f * x * (1.0f + th);
}

__device__ __forceinline__ void gl_lds16(const void* g, void* l) {
    __builtin_amdgcn_global_load_lds(
        (const __attribute__((address_space(1))) void*)g,
        (__attribute__((address_space(3))) void*)l, 16, 0, 0);
}

// ---------------- x fp32 -> bf16 ----------------
__global__ __launch_bounds__(256)
void conv_x_kernel(const float* __restrict__ in, unsigned short* __restrict__ outp, int n8) {
    for (int i = blockIdx.x * 256 + threadIdx.x; i < n8; i += gridDim.x * 256) {
        const float4* pp = reinterpret_cast<const float4*>(in + (size_t)i * 8);
        float4 a = pp[0], b = pp[1];
        u16x8 o;
        o[0]=f2bf(a.x); o[1]=f2bf(a.y); o[2]=f2bf(a.z); o[3]=f2bf(a.w);
        o[4]=f2bf(b.x); o[5]=f2bf(b.y); o[6]=f2bf(b.z); o[7]=f2bf(b.w);
        *reinterpret_cast<u16x8*>(outp + (size_t)i * 8) = o;
    }
}

// ---------------- [E][R][C] fp32 -> [E][C][R] bf16 ----------------
__global__ __launch_bounds__(256)
void transpose_conv(const float* __restrict__ in, unsigned short* __restrict__ outp, int R, int C) {
    __shared__ float tile[32][33];
    size_t mat = (size_t)R * C;
    const float* src = in + (size_t)blockIdx.z * mat;
    unsigned short* dst = outp + (size_t)blockIdx.z * mat;
    int c0 = blockIdx.x * 32, r0 = blockIdx.y * 32;
    int tc = threadIdx.x & 31, tr = threadIdx.x >> 5;
#pragma unroll
    for (int i = 0; i < 4; ++i)
        tile[tr + i*8][tc] = src[(size_t)(r0 + tr + i*8) * C + (c0 + tc)];
    __syncthreads();
#pragma unroll
    for (int i = 0; i < 4; ++i) {
        int a = tr + i*8;
        dst[(size_t)(c0 + a) * R + (r0 + tc)] = f2bf(tile[tc][a]);
    }
}

// ---------------- gating: fp32 logits, top-2, softmax ----------------
__global__ __launch_bounds__(256)
void gate_kernel(const float* __restrict__ x, const float* __restrict__ gW,
                 const float* __restrict__ gb, float* __restrict__ outIdx,
                 int* __restrict__ tokE, float* __restrict__ tokW, int* __restrict__ counts) {
    int wave = threadIdx.x >> 6, lane = threadIdx.x & 63;
    int tok = blockIdx.x * 4 + wave;
    const float* xr = x + (size_t)tok * DIM;
    float p[NE];
#pragma unroll
    for (int e = 0; e < NE; ++e) p[e] = 0.f;
    for (int i = lane; i < DIM; i += 64) {
        float xi = xr[i];
        const float* g = gW + (size_t)i * NE;
#pragma unroll
        for (int e = 0; e < NE; ++e) p[e] += xi * g[e];
    }
#pragma unroll
    for (int off = 32; off > 0; off >>= 1) {
#pragma unroll
        for (int e = 0; e < NE; ++e) p[e] += __shfl_xor(p[e], off, 64);
    }
    if (lane == 0) {
        float v0 = -1e30f, v1 = -1e30f; int i0 = 0, i1 = 0;
#pragma unroll
        for (int e = 0; e < NE; ++e) {
            float l = p[e] + gb[e];
            if (l > v0)      { v1 = v0; i1 = i0; v0 = l; i0 = e; }
            else if (l > v1) { v1 = l; i1 = e; }
        }
        float e1 = expf(v1 - v0);
        float inv = 1.0f / (1.0f + e1);
        outIdx[tok*2]   = (float)i0;
        outIdx[tok*2+1] = (float)i1;
        tokE[tok*2] = i0; tokE[tok*2+1] = i1;
        tokW[tok*2] = inv; tokW[tok*2+1] = e1 * inv;
        atomicAdd(&counts[i0], 1);
        atomicAdd(&counts[i1], 1);
    }
}

// ---------------- offsets (parallel) + pad-slot init ----------------
__global__ __launch_bounds__(256)
void offsets_kernel(const int* __restrict__ counts, int* __restrict__ P,
                    int* __restrict__ tileinfo, int* __restrict__ rowlist,
                    float* __restrict__ slotW) {
    __shared__ int ts[NE+1], cn[NE];
    int t = threadIdx.x;
    if (t == 0) {
        int off = 0;
        for (int e = 0; e < NE; ++e) {
            int c = counts[e];
            cn[e] = c; ts[e] = off; P[e] = off;
            off += ((c + 255) >> 8) << 8;
        }
        ts[NE] = off;
    }
    __syncthreads();
    int total = ts[NE];
    for (int ti = t; ti < MAXT2; ti += 256) {
        int s0 = ti * 256;
        if (s0 < total) {
            int e = 0;
#pragma unroll
            for (int q = 1; q < NE; ++q) if (s0 >= ts[q]) e = q;
            int v = cn[e] - (s0 - ts[e]);
            tileinfo[ti*4+0] = e;
            tileinfo[ti*4+1] = s0;
            tileinfo[ti*4+2] = v > 256 ? 256 : v;
        } else tileinfo[ti*4+0] = -1;
    }
    // zero pad slots so GEMM A-gather / epilogue gather are clean
    for (int s = t; s < total; s += 256) {
        int e = 0;
#pragma unroll
        for (int q = 1; q < NE; ++q) if (s >= ts[q]) e = q;
        if (s - ts[e] >= cn[e]) { rowlist[s] = 0; slotW[s] = 0.f; }
    }
}

// ---------------- scatter tokens into per-expert row lists ----------------
__global__ __launch_bounds__(256)
void scatter_kernel(const int* __restrict__ tokE, const float* __restrict__ tokW,
                    const int* __restrict__ P, int* __restrict__ cursor,
                    int* __restrict__ rowlist, float* __restrict__ slotW) {
    int tk = blockIdx.x * 256 + threadIdx.x;
    if (tk >= N_TOK) return;
#pragma unroll
    for (int k = 0; k < 2; ++k) {
        int e = tokE[tk*2 + k];
        int pos = atomicAdd(&cursor[e], 1);
        int slot = P[e] + pos;
        rowlist[slot] = tk;
        slotW[slot]  = tokW[tk*2 + k];
    }
}

// ============ 256x256 8-phase grouped GEMM (T2+T3+T4+T5+T1) ============
// 8 waves (2M x 4N), wave tile 128x64, BK=64, LDS 128KB double-buffered.
// LDS halves: A rows 0-127 / 128-255; B rows (cols of C) 0-127 / 128-255.
// Swizzle: 16B chunk index ^= (row&7) on BOTH stage-source and ds_read.
// Stage schedule (iter i computes K-tiles 2i,2i+1): ph1 Blo[2i+1], ph2 Bhi[2i+1],
// ph3 Alo[2i+2], ph4 Ahi[2i+2], ph5 Blo[2i+2], ph6 Bhi[2i+2], ph7 Alo[2i+3],
// ph8 Ahi[2i+3]; vmcnt(4) at ph4 & ph8 only (counted, never 0 mid-loop).

#define BAR()  do { __builtin_amdgcn_s_barrier(); __builtin_amdgcn_sched_barrier(0); } while(0)
#define LGK0() do { asm volatile("s_waitcnt lgkmcnt(0)" ::: "memory"); __builtin_amdgcn_sched_barrier(0); } while(0)
#define VMC4() do { asm volatile("s_waitcnt vmcnt(4)" ::: "memory"); __builtin_amdgcn_sched_barrier(0); } while(0)
#define VMC0() do { asm volatile("s_waitcnt vmcnt(0)" ::: "memory"); __builtin_amdgcn_sched_barrier(0); } while(0)

#define STAGE(MAT, H, KT) do { \
    char* _d = smem + (((KT)&1)*65536) + ((MAT)*32768) + ((H)*16384) + wave*1024; \
    _Pragma("unroll") \
    for (int _j = 0; _j < 2; ++_j) { \
        const unsigned short* _g = ((MAT) ? Bexp : Amat) + ((MAT) ? boff[H][_j] : aoff[H][_j]) + (KT)*64; \
        gl_lds16(_g, _d + _j*8192); \
    } } while(0)

#define LDA(DST, SB, MH) do { \
    _Pragma("unroll") \
    for (int _mf = 0; _mf < 4; ++_mf) { \
        DST[_mf][0] = *(const bf16x8*)((SB) + abase + (MH)*8192 + _mf*2048 + ck0); \
        DST[_mf][1] = *(const bf16x8*)((SB) + abase + (MH)*8192 + _mf*2048 + ck1); \
    } } while(0)

#define LDB(DST, SB, NH) do { \
    _Pragma("unroll") \
    for (int _nf = 0; _nf < 2; ++_nf) { \
        DST[_nf][0] = *(const bf16x8*)((SB) + bbase + ((NH)*2+_nf)*2048 + ck0); \
        DST[_nf][1] = *(const bf16x8*)((SB) + bbase + ((NH)*2+_nf)*2048 + ck1); \
    } } while(0)

#define MMA(MH, NH, A_, B_) do { \
    __builtin_amdgcn_s_setprio(1); \
    _Pragma("unroll") \
    for (int _ks = 0; _ks < 2; ++_ks) \
    _Pragma("unroll") \
    for (int _mf = 0; _mf < 4; ++_mf) \
    _Pragma("unroll") \
    for (int _nf = 0; _nf < 2; ++_nf) \
        acc[(MH)*4+_mf][(NH)*2+_nf] = __builtin_amdgcn_mfma_f32_16x16x32_bf16( \
            A_[_mf][_ks], B_[_nf][_ks], acc[(MH)*4+_mf][(NH)*2+_nf], 0, 0, 0); \
    __builtin_amdgcn_s_setprio(0); } while(0)

template<int MODE>   // 1: x@W1 -> gelu -> h ; 2: h@W2 -> weighted atomic out
__global__ __launch_bounds__(512, 2)
void moe_gemm256(const unsigned short* __restrict__ Amat,
                 const unsigned short* __restrict__ Bmat,
                 const float* __restrict__ bias,
                 const int* __restrict__ tileinfo,
                 const int* __restrict__ rowlist,
                 const float* __restrict__ slotW,
                 unsigned short* __restrict__ hout,
                 float* __restrict__ outp)
{
    constexpr int KD    = (MODE == 1) ? DIM : DFF_;
    constexpr int ND    = (MODE == 1) ? DFF_ : DIM;
    constexpr int NKT   = KD / 64;
    constexpr int NITER = NKT / 2;

    // XCD-aware tile swizzle (grid.x = 136 = 8*17, bijective)
    int bx  = blockIdx.x;
    int per = gridDim.x >> 3;
    int bxs = (bx & 7) * per + (bx >> 3);
    int e = tileinfo[bxs*4];
    if (e < 0) return;
    int base   = tileinfo[bxs*4+1];
    int nvalid = tileinfo[bxs*4+2];
    int colBlk = blockIdx.y;

    extern __shared__ char smem[];   // 131072 B

    int tid = threadIdx.x;
    int wave = tid >> 6, lane = tid & 63;
    int wr = wave >> 2, wc = wave & 3;

    // staging source element-offsets; chunk pre-swizzled so linear LDS dest
    // ends up holding the swizzled layout (rule #21 involution)
    int srow = tid >> 3;                       // 0..63
    int schunk = (tid & 7) ^ (srow & 7);
    unsigned aoff[2][2], boff[2][2];
#pragma unroll
    for (int h = 0; h < 2; ++h)
#pragma unroll
    for (int j = 0; j < 2; ++j) {
        int r = h*128 + j*64 + srow;           // row within 256-row tile
        unsigned arow;
        if constexpr (MODE == 1) arow = (unsigned)rowlist[base + r] * KD;   // gather
        else                     arow = (unsigned)(base + r) * KD;          // direct
        aoff[h][j] = arow + schunk*8;
        boff[h][j] = (unsigned)(colBlk*256 + r) * KD + schunk*8;
    }
    const unsigned short* Bexp = Bmat + (size_t)e * ND * KD;

    // fragment read bases (swizzled): row&7 == lane&7 for all frag rows
    int fr = lane & 15, fq = lane >> 4;
    int abase = wr*16384 + fr*128;
    int bbase = 32768 + (wc >> 1)*16384 + (wc & 1)*8192 + fr*128;
    int ck0 = ((0*4 + fq) ^ (lane & 7)) * 16;
    int ck1 = ((1*4 + fq) ^ (lane & 7)) * 16;

    f32x4 acc[8][4] = {};

    // prologue: full K-tile 0 (buf0) + A halves of K-tile 1 (buf1)
    STAGE(0,0,0); STAGE(0,1,0); STAGE(1,0,0); STAGE(1,1,0);
    STAGE(0,0,1); STAGE(0,1,1);
    VMC4();       // 12 loads out, wait to 4 -> buf0 fully landed
    BAR();

    for (int i = 0; i < NITER; ++i) {
        const int kt1 = 2*i + 1;
        const bool pf = (i < NITER - 1);
        char* s0 = smem;
        char* s1 = smem + 65536;
        bf16x8 a0[4][2], a1[4][2], b0[2][2], b1[2][2];

        // ---- K-tile 2i (buf0), serpentine quadrants ----
        // ph1: (mh0,nh0)
        LDA(a0, s0, 0); LDB(b0, s0, 0);
        STAGE(1,0,kt1);
        BAR(); LGK0();
        MMA(0,0,a0,b0);
        BAR();
        // ph2: (mh1,nh0)
        LDA(a1, s0, 1);
        STAGE(1,1,kt1);
        BAR(); LGK0();
        MMA(1,0,a1,b0);
        BAR();
        // ph3: (mh1,nh1)
        LDB(b1, s0, 1);
        if (pf) STAGE(0,0,kt1+1);
        BAR(); LGK0();
        MMA(1,1,a1,b1);
        BAR();
        // ph4: (mh0,nh1) — no ds_reads
        if (pf) STAGE(0,1,kt1+1);
        BAR();
        MMA(0,1,a0,b1);
        if (pf) { VMC4(); } else { VMC0(); }
        BAR();

        // ---- K-tile 2i+1 (buf1) ----
        // ph5
        LDA(a0, s1, 0); LDB(b0, s1, 0);
        if (pf) STAGE(1,0,kt1+1);
        BAR(); LGK0();
        MMA(0,0,a0,b0);
        BAR();
        // ph6
        LDA(a1, s1, 1);
        if (pf) STAGE(1,1,kt1+1);
        BAR(); LGK0();
        MMA(1,0,a1,b0);
        BAR();
        // ph7
        LDB(b1, s1, 1);
        if (pf) STAGE(0,0,kt1+2);
        BAR(); LGK0();
        MMA(1,1,a1,b1);
        BAR();
        // ph8
        if (pf) STAGE(0,1,kt1+2);
        BAR();
        MMA(0,1,a0,b1);
        if (pf) { VMC4(); } else { VMC0(); }
        BAR();
    }

    // ---------------- epilogue ----------------
    float bcol[4];
#pragma unroll
    for (int n = 0; n < 4; ++n)
        bcol[n] = bias[(size_t)e*ND + colBlk*256 + wc*64 + n*16 + fr];

#pragma unroll
    for (int m = 0; m < 8; ++m) {
        int rbase = wr*128 + (m >> 2)*64 + (m & 3)*16 + fq*4;  // A-frag row map
#pragma unroll
        for (int j = 0; j < 4; ++j) {
            int grow = rbase + j;
            if constexpr (MODE == 1) {
                size_t hrow = (size_t)(base + grow) * ND + colBlk*256;
#pragma unroll
                for (int n = 0; n < 4; ++n) {
                    unsigned short val = 0;
                    if (grow < nvalid)
                        val = f2bf(gelu_t(acc[m][n][j] + bcol[n]));
                    hout[hrow + wc*64 + n*16 + fr] = val;
                }
            } else {
                if (grow < nvalid) {
                    int tok = rowlist[base + grow];
                    float w = slotW[base + grow];
                    size_t orow = (size_t)tok * DIM + colBlk*256;
#pragma unroll
                    for (int n = 0; n < 4; ++n)
                        atomicAdd(outp + orow + wc*64 + n*16 + fr,
                                  w * (acc[m][n][j] + bcol[n]));
                }
            }
        }
    }
}

#undef BAR
#undef LGK0
#undef VMC4
#undef VMC0
#undef STAGE
#undef LDA
#undef LDB
#undef MMA

extern "C" void kernel_launch(void* const* d_in, const int* in_sizes, int n_in,
                              void* d_out, int out_size, void* d_ws, size_t ws_size,
                              hipStream_t stream) {
    const float* x  = (const float*)d_in[0];
    const float* gW = (const float*)d_in[1];
    const float* gb = (const float*)d_in[2];
    const float* W1 = (const float*)d_in[3];
    const float* b1 = (const float*)d_in[4];
    const float* W2 = (const float*)d_in[5];
    const float* b2 = (const float*)d_in[6];
    float* outp = (float*)d_out;

    char* ws = (char*)d_ws;
    size_t off = 0;
    auto alloc = [&](size_t bytes) { void* p = ws + off; off += (bytes + 511) & ~(size_t)511; return p; };
    unsigned short* xb   = (unsigned short*)alloc((size_t)N_TOK * DIM * 2);
    unsigned short* W1t  = (unsigned short*)alloc((size_t)NE * DFF_ * DIM * 2);
    unsigned short* W2t  = (unsigned short*)alloc((size_t)NE * DIM * DFF_ * 2);
    unsigned short* hbuf = (unsigned short*)alloc((size_t)MAXSLOTS2 * DFF_ * 2);
    int*   rowlist = (int*)alloc(MAXSLOTS2 * 4);
    float* slotW   = (float*)alloc(MAXSLOTS2 * 4);
    int*   tokE    = (int*)alloc(N_TOK * 2 * 4);
    float* tokW    = (float*)alloc(N_TOK * 2 * 4);
    int*   meta    = (int*)alloc(8192);
    int* counts   = meta;        // 8
    int* cursor   = meta + 8;    // 8
    int* Parr     = meta + 16;   // 8
    int* tileinfo = meta + 32;   // MAXT2*4

    hipMemsetAsync(meta, 0, 8192, stream);
    hipMemsetAsync(outp, 0, (size_t)N_TOK * DIM * sizeof(float), stream);

    conv_x_kernel<<<2048, 256, 0, stream>>>(x, xb, N_TOK * DIM / 8);
    transpose_conv<<<dim3(DFF_/32, DIM/32, NE), 256, 0, stream>>>(W1, W1t, DIM, DFF_);
    transpose_conv<<<dim3(DIM/32, DFF_/32, NE), 256, 0, stream>>>(W2, W2t, DFF_, DIM);

    gate_kernel<<<N_TOK/4, 256, 0, stream>>>(x, gW, gb, outp + (size_t)N_TOK * DIM,
                                             tokE, tokW, counts);
    offsets_kernel<<<1, 256, 0, stream>>>(counts, Parr, tileinfo, rowlist, slotW);
    scatter_kernel<<<N_TOK/256, 256, 0, stream>>>(tokE, tokW, Parr, cursor, rowlist, slotW);

    (void)hipFuncSetAttribute((const void*)moe_gemm256<1>,
                              hipFuncAttributeMaxDynamicSharedMemorySize, 131072);
    (void)hipFuncSetAttribute((const void*)moe_gemm256<2>,
                              hipFuncAttributeMaxDynamicSharedMemorySize, 131072);

    moe_gemm256<1><<<dim3(MAXT2, DFF_/256), 512, 131072, stream>>>(
        xb, W1t, b1, tileinfo, rowlist, slotW, hbuf, nullptr);
    moe_gemm256<2><<<dim3(MAXT2, DIM/256), 512, 131072, stream>>>(
        hbuf, W2t, b2, tileinfo, rowlist, slotW, nullptr, outp);
}